// Round 8
// baseline (208.345 us; speedup 1.0000x reference)
//
#include <hip/hip_runtime.h>
#include <hip/hip_bf16.h>

#define TFULL 4096
#define NBATCH 8
#define INDIM 128
#define OUTDIM 128
#define HIDDIM 256
#define LCH 64
#define NCH (TFULL / LCH)   // 64

typedef float f32x4 __attribute__((ext_vector_type(4)));
typedef short short8 __attribute__((ext_vector_type(8)));

static __device__ __forceinline__ unsigned short f2bf(float f) {
    unsigned int x = __float_as_uint(f);
    x += 0x7fffu + ((x >> 16) & 1u);   // round-to-nearest-even
    return (unsigned short)(x >> 16);
}
static __device__ __forceinline__ unsigned int pack2(float a, float b) {
    return ((unsigned int)f2bf(b) << 16) | (unsigned int)f2bf(a);
}
static __device__ __forceinline__ float bflo(unsigned int u) {
    return __uint_as_float(u << 16);
}
static __device__ __forceinline__ float bfhi(unsigned int u) {
    return __uint_as_float(u & 0xffff0000u);
}
// split fp32 into hi/lo bf16 pair (v ~= hi + lo to ~16.5 mantissa bits)
static __device__ __forceinline__ void split2(float v, unsigned short& hi, unsigned short& lo) {
    hi = f2bf(v);
    lo = f2bf(v - __uint_as_float((unsigned int)hi << 16));
}

// ---------------------------------------------------------------------------
// K0 (proven): precompute hi/lo bf16 weights + lam^(t+1) table.
// ---------------------------------------------------------------------------
__global__ __launch_bounds__(256) void k_prep(
    const float* __restrict__ nu_log, const float* __restrict__ theta_log,
    const float* __restrict__ B_re, const float* __restrict__ B_im,
    const float* __restrict__ C_re, const float* __restrict__ C_im,
    const float* __restrict__ D,
    unsigned short* __restrict__ Wbx_hi, unsigned short* __restrict__ Wbx_lo,
    unsigned short* __restrict__ Wy_hi, unsigned short* __restrict__ Wy_lo,
    float2* __restrict__ lampow)
{
    int f = blockIdx.x * 256 + threadIdx.x;   // grid 640 -> f < 163840
    if (f < 65536) {
        int kk = f & 31, n = (f >> 5) & 255, kc = (f >> 13) & 3, half = f >> 15;
        int g = n >> 6;
        int h = 128 * half + 64 * (g >> 1) + (n & 63);
        int i = 32 * kc + kk;
        float mag = expf(-expf(nu_log[h]));
        float gam = sqrtf(fmaxf(0.f, 1.f - mag * mag));
        float v = gam * ((g & 1) ? B_im[h * INDIM + i] : B_re[h * INDIM + i]);
        unsigned short hi, lo; split2(v, hi, lo);
        Wbx_hi[f] = hi; Wbx_lo[f] = lo;
    } else if (f < 147456) {
        int q = f - 65536;
        int kk = q & 63, o = (q >> 6) & 127, kc = q >> 13;
        int k = 64 * kc + kk;
        float v;
        if (k < 512) {
            int h = k >> 1;
            v = (k & 1) ? -C_im[o * HIDDIM + h] : C_re[o * HIDDIM + h];
        } else {
            v = D[o * INDIM + (k - 512)];
        }
        unsigned short hi, lo; split2(v, hi, lo);
        Wy_hi[q] = hi; Wy_lo[q] = lo;
    } else {
        int l = f - 147456;                   // [0, 16384)
        int h = l & 255, tl = l >> 8;
        float nu = expf(nu_log[h]), th = expf(theta_log[h]);
        float kf = (float)(tl + 1);
        float m = expf(-kf * nu);
        lampow[l] = make_float2(m * cosf(kf * th), m * sinf(kf * th));
    }
}

// ---------------------------------------------------------------------------
// K1a (R7-proven + T14 async-STAGE split): split-precision MFMA GEMM BX
//      (M=64 t, N=256, K=128) per (b, chunk, h-half). Loads for chunk kc+1
//      are issued during the MFMA phase of chunk kc; LDS writes happen after
//      the barrier. Index math / MFMA sequence verbatim from R7.
// ---------------------------------------------------------------------------
__global__ __launch_bounds__(256) void k_bx(
    const float* __restrict__ X,
    const unsigned short* __restrict__ Wbx_hi,
    const unsigned short* __restrict__ Wbx_lo,
    float2* __restrict__ BX)
{
    __shared__ unsigned short sm[25600];   // 51200 B
    unsigned short* Ash = sm;              // [64][40]
    unsigned short* Asl = sm + 2560;       // [64][40]
    unsigned short* Bsh = sm + 5120;       // [256][40]
    unsigned short* Bsl = sm + 15360;      // [256][40]

    const int tid = threadIdx.x;
    const int blk = blockIdx.x;
    const int b = blk >> 7, c = (blk >> 1) & 63, half = blk & 1;
    const size_t rowbase = (size_t)(b * TFULL + c * LCH);

    f32x4 acc[2][8];
    #pragma unroll
    for (int mi = 0; mi < 2; ++mi)
        #pragma unroll
        for (int j = 0; j < 8; ++j) acc[mi][j] = (f32x4){0.f, 0.f, 0.f, 0.f};

    const int w = tid >> 6, l = tid & 63;
    const int wm = w >> 1, wn = w & 1;
    const int lr = l & 15, lk = l >> 4;
    const unsigned short* wch_h = Wbx_hi + half * 32768;
    const unsigned short* wch_l = Wbx_lo + half * 32768;

    // ---- prologue: issue loads for kc=0 ----
    uint4 pvh[4], pvl[4];
    float4 pxa, pxb;
    {
        const uint4* sh = (const uint4*)(wch_h);
        const uint4* sl = (const uint4*)(wch_l);
        #pragma unroll
        for (int j = 0; j < 4; ++j) { pvh[j] = sh[tid + j * 256]; pvl[j] = sl[tid + j * 256]; }
        const float* Xr = X + (rowbase + (tid >> 2)) * INDIM + 8 * (tid & 3);
        pxa = *(const float4*)(Xr);
        pxb = *(const float4*)(Xr + 4);
    }

    for (int kc = 0; kc < 4; ++kc) {
        // ---- write phase: commit prefetched B/A to LDS ----
        #pragma unroll
        for (int j = 0; j < 4; ++j) {
            int n = (tid >> 2) + 64 * j, kq = 8 * (tid & 3);
            *(uint4*)(Bsh + n * 40 + kq) = pvh[j];
            *(uint4*)(Bsl + n * 40 + kq) = pvl[j];
        }
        {
            int t = tid >> 2, q = tid & 3;
            float xs[8] = {pxa.x, pxa.y, pxa.z, pxa.w, pxb.x, pxb.y, pxb.z, pxb.w};
            unsigned int* Ah32 = (unsigned int*)Ash + t * 20 + 4 * q;
            unsigned int* Al32 = (unsigned int*)Asl + t * 20 + 4 * q;
            #pragma unroll
            for (int e = 0; e < 4; ++e) {
                unsigned short h0, l0, h1, l1;
                split2(xs[2 * e], h0, l0);
                split2(xs[2 * e + 1], h1, l1);
                Ah32[e] = ((unsigned int)h1 << 16) | h0;
                Al32[e] = ((unsigned int)l1 << 16) | l0;
            }
        }
        __syncthreads();
        // ---- issue loads for kc+1 (land during MFMA phase) ----
        if (kc < 3) {
            const uint4* sh = (const uint4*)(wch_h + (kc + 1) * 8192);
            const uint4* sl = (const uint4*)(wch_l + (kc + 1) * 8192);
            #pragma unroll
            for (int j = 0; j < 4; ++j) { pvh[j] = sh[tid + j * 256]; pvl[j] = sl[tid + j * 256]; }
            const float* Xr = X + (rowbase + (tid >> 2)) * INDIM + 32 * (kc + 1) + 8 * (tid & 3);
            pxa = *(const float4*)(Xr);
            pxb = *(const float4*)(Xr + 4);
        }
        // ---- MFMA: split-precision (3 products), verbatim ----
        short8 a0h = *(const short8*)(Ash + (32 * wm + lr) * 40 + 8 * lk);
        short8 a1h = *(const short8*)(Ash + (32 * wm + 16 + lr) * 40 + 8 * lk);
        short8 a0l = *(const short8*)(Asl + (32 * wm + lr) * 40 + 8 * lk);
        short8 a1l = *(const short8*)(Asl + (32 * wm + 16 + lr) * 40 + 8 * lk);
        #pragma unroll
        for (int j = 0; j < 8; ++j) {
            short8 bh = *(const short8*)(Bsh + (128 * wn + 16 * j + lr) * 40 + 8 * lk);
            short8 bl = *(const short8*)(Bsl + (128 * wn + 16 * j + lr) * 40 + 8 * lk);
            acc[0][j] = __builtin_amdgcn_mfma_f32_16x16x32_bf16(a0h, bh, acc[0][j], 0, 0, 0);
            acc[0][j] = __builtin_amdgcn_mfma_f32_16x16x32_bf16(a0l, bh, acc[0][j], 0, 0, 0);
            acc[0][j] = __builtin_amdgcn_mfma_f32_16x16x32_bf16(a0h, bl, acc[0][j], 0, 0, 0);
            acc[1][j] = __builtin_amdgcn_mfma_f32_16x16x32_bf16(a1h, bh, acc[1][j], 0, 0, 0);
            acc[1][j] = __builtin_amdgcn_mfma_f32_16x16x32_bf16(a1l, bh, acc[1][j], 0, 0, 0);
            acc[1][j] = __builtin_amdgcn_mfma_f32_16x16x32_bf16(a1h, bl, acc[1][j], 0, 0, 0);
        }
        __syncthreads();
    }

    // ---- store BX fp32: h = 128*half + 64*wn + 16*j + lr ----
    #pragma unroll
    for (int mi = 0; mi < 2; ++mi)
        #pragma unroll
        for (int j = 0; j < 4; ++j)
            #pragma unroll
            for (int r = 0; r < 4; ++r) {
                int t = 32 * wm + 16 * mi + 4 * lk + r;
                int h = 128 * half + 64 * wn + 16 * j + lr;
                BX[(rowbase + t) * HIDDIM + h] =
                    make_float2(acc[mi][j][r], acc[mi][j + 4][r]);
            }
}

// ---------------------------------------------------------------------------
// K1b (R7-proven): pipelined sequential scan; bf16x2 h out; chunk-end -> EC.
// ---------------------------------------------------------------------------
__global__ __launch_bounds__(256) void k_scan(
    const float* __restrict__ nu_log, const float* __restrict__ theta_log,
    const float2* __restrict__ BX, unsigned int* __restrict__ hloc,
    float2* __restrict__ EC)
{
    const int b = blockIdx.x >> 6, c = blockIdx.x & 63;
    const int h = threadIdx.x;
    const size_t rowbase = (size_t)(b * TFULL + c * LCH);

    float nu = expf(nu_log[h]), th = expf(theta_log[h]);
    float mag = expf(-nu);
    float lre = mag * cosf(th), lim = mag * sinf(th);
    float sre = 0.f, sim = 0.f;
    const float2* p = BX + rowbase * HIDDIM + h;
    unsigned int* q = hloc + rowbase * HIDDIM + h;
    for (int t0 = 0; t0 < LCH; t0 += 8) {
        float2 v[8];
        #pragma unroll
        for (int j = 0; j < 8; ++j) v[j] = p[(size_t)(t0 + j) * HIDDIM];
        unsigned int o[8];
        #pragma unroll
        for (int j = 0; j < 8; ++j) {
            float nre = fmaf(lre, sre, fmaf(-lim, sim, v[j].x));
            float nim = fmaf(lre, sim, fmaf(lim, sre, v[j].y));
            sre = nre; sim = nim;
            o[j] = pack2(sre, sim);
        }
        #pragma unroll
        for (int j = 0; j < 8; ++j) q[(size_t)(t0 + j) * HIDDIM] = o[j];
    }
    EC[((size_t)b * NCH + c) * HIDDIM + h] = make_float2(sre, sim);
}

// ---------------------------------------------------------------------------
// K2 (R7-proven): pipelined serial carry.
// ---------------------------------------------------------------------------
__global__ __launch_bounds__(256) void k_carry(
    const float* __restrict__ nu_log, const float* __restrict__ theta_log,
    float2* __restrict__ EC)
{
    int b = blockIdx.x, h = threadIdx.x;
    float nu = expf(nu_log[h]), th = expf(theta_log[h]);
    float m = expf(-(float)LCH * nu);
    float Lre = m * cosf((float)LCH * th);
    float Lim = m * sinf((float)LCH * th);
    float cre = 0.f, cim = 0.f;
    float2* base = EC + (size_t)b * NCH * HIDDIM + h;
    for (int c0 = 0; c0 < NCH; c0 += 8) {
        float2 e[8];
        #pragma unroll
        for (int j = 0; j < 8; ++j) e[j] = base[(size_t)(c0 + j) * HIDDIM];
        float2 wv[8];
        #pragma unroll
        for (int j = 0; j < 8; ++j) {
            wv[j] = make_float2(cre, cim);
            float nre = e[j].x + Lre * cre - Lim * cim;
            float nim = e[j].y + Lre * cim + Lim * cre;
            cre = nre; cim = nim;
        }
        #pragma unroll
        for (int j = 0; j < 8; ++j) base[(size_t)(c0 + j) * HIDDIM] = wv[j];
    }
}

// ---------------------------------------------------------------------------
// K3 (R7-proven + T14 async-STAGE split): split-precision MFMA GEMM Y
//     (M=64 t, N=128 o, K=640). Loads for kc+1 (Wy hi/lo, hloc+lampow or X)
//     issued during the MFMA phase of kc; fixup + LDS writes after barrier.
//     Index math / MFMA sequence verbatim from R7.
// ---------------------------------------------------------------------------
__global__ __launch_bounds__(256) void k_y(
    const float* __restrict__ X, const unsigned int* __restrict__ hloc,
    const float2* __restrict__ EC, const float2* __restrict__ lampow,
    const unsigned short* __restrict__ Wy_hi,
    const unsigned short* __restrict__ Wy_lo, float* __restrict__ Y)
{
    __shared__ unsigned short sm[27648];  // 55296 B
    unsigned short* Ah = sm;              // [64][72]
    unsigned short* Al = sm + 4608;       // [64][72]
    unsigned short* Bh = sm + 9216;       // [128][72]
    unsigned short* Bl = sm + 18432;      // [128][72]
    __shared__ float2 carryS[256];

    const int tid = threadIdx.x;
    const int b = blockIdx.x >> 6, c = blockIdx.x & 63;
    const size_t rowbase = (size_t)(b * TFULL + c * LCH);

    carryS[tid] = EC[((size_t)b * NCH + c) * HIDDIM + tid];

    f32x4 acc[2][4];
    #pragma unroll
    for (int mi = 0; mi < 2; ++mi)
        #pragma unroll
        for (int nj = 0; nj < 4; ++nj) acc[mi][nj] = (f32x4){0.f, 0.f, 0.f, 0.f};

    const int w = tid >> 6, l = tid & 63;
    const int wm = w >> 1, wn = w & 1;
    const int lr = l & 15, lk = l >> 4;

    // ---- prologue: issue loads for kc=0 (hloc branch) ----
    uint4 pbh[4], pbl[4];
    uint4 pha[2];
    float2 plp[2][4];
    float4 pxv[4];
    {
        const uint4* sh = (const uint4*)(Wy_hi);
        const uint4* sl = (const uint4*)(Wy_lo);
        #pragma unroll
        for (int j = 0; j < 4; ++j) { pbh[j] = sh[tid + j * 256]; pbl[j] = sl[tid + j * 256]; }
        #pragma unroll
        for (int s = 0; s < 2; ++s) {
            int f = s * 256 + tid;
            int t = f >> 3, slot = f & 7;
            pha[s] = *(const uint4*)(hloc + (rowbase + t) * HIDDIM + 4 * slot);
            #pragma unroll
            for (int e = 0; e < 4; ++e)
                plp[s][e] = lampow[t * HIDDIM + 4 * slot + e];
        }
    }
    __syncthreads();   // carryS ready before first write-phase use

    for (int kc = 0; kc < 10; ++kc) {
        // ---- write phase: commit prefetched B to LDS ----
        #pragma unroll
        for (int j = 0; j < 4; ++j) {
            int o = (tid >> 3) + 32 * j, kq = 8 * (tid & 7);
            *(uint4*)(Bh + o * 72 + kq) = pbh[j];
            *(uint4*)(Bl + o * 72 + kq) = pbl[j];
        }
        // ---- write phase: fixup + commit prefetched A to LDS ----
        if (kc < 8) {
            #pragma unroll
            for (int s = 0; s < 2; ++s) {
                int f = s * 256 + tid;
                int t = f >> 3, slot = f & 7;
                unsigned int* Arh = (unsigned int*)Ah + t * 36 + 4 * slot;
                unsigned int* Arl = (unsigned int*)Al + t * 36 + 4 * slot;
                const unsigned int* uu = (const unsigned int*)&pha[s];
                #pragma unroll
                for (int e = 0; e < 4; ++e) {
                    int h = 32 * kc + 4 * slot + e;
                    float2 lp = plp[s][e];
                    float2 cr = carryS[h];
                    float hre = bflo(uu[e]) + lp.x * cr.x - lp.y * cr.y;
                    float him = bfhi(uu[e]) + lp.x * cr.y + lp.y * cr.x;
                    unsigned short rh, rl, ih, il;
                    split2(hre, rh, rl); split2(him, ih, il);
                    Arh[e] = ((unsigned int)ih << 16) | rh;
                    Arl[e] = ((unsigned int)il << 16) | rl;
                }
            }
        } else {
            #pragma unroll
            for (int s = 0; s < 4; ++s) {
                int f = s * 256 + tid;
                int t = f >> 4, slot = f & 15;
                float4 v = pxv[s];
                unsigned short h0,l0,h1,l1,h2,l2,h3,l3;
                split2(v.x,h0,l0); split2(v.y,h1,l1); split2(v.z,h2,l2); split2(v.w,h3,l3);
                unsigned int* Arh = (unsigned int*)Ah + t * 36 + 2 * slot;
                unsigned int* Arl = (unsigned int*)Al + t * 36 + 2 * slot;
                Arh[0] = ((unsigned int)h1 << 16) | h0;
                Arh[1] = ((unsigned int)h3 << 16) | h2;
                Arl[0] = ((unsigned int)l1 << 16) | l0;
                Arl[1] = ((unsigned int)l3 << 16) | l2;
            }
        }
        __syncthreads();
        // ---- issue loads for kc+1 (land during MFMA phase) ----
        if (kc < 9) {
            const uint4* sh = (const uint4*)(Wy_hi + (kc + 1) * 8192);
            const uint4* sl = (const uint4*)(Wy_lo + (kc + 1) * 8192);
            #pragma unroll
            for (int j = 0; j < 4; ++j) { pbh[j] = sh[tid + j * 256]; pbl[j] = sl[tid + j * 256]; }
            if (kc + 1 < 8) {
                #pragma unroll
                for (int s = 0; s < 2; ++s) {
                    int f = s * 256 + tid;
                    int t = f >> 3, slot = f & 7;
                    pha[s] = *(const uint4*)(hloc + (rowbase + t) * HIDDIM + 32 * (kc + 1) + 4 * slot);
                    #pragma unroll
                    for (int e = 0; e < 4; ++e)
                        plp[s][e] = lampow[t * HIDDIM + 32 * (kc + 1) + 4 * slot + e];
                }
            } else {
                int i0 = (kc + 1 - 8) * 64;
                #pragma unroll
                for (int s = 0; s < 4; ++s) {
                    int f = s * 256 + tid;
                    int t = f >> 4, slot = f & 15;
                    pxv[s] = *(const float4*)(X + (rowbase + t) * INDIM + i0 + 4 * slot);
                }
            }
        }
        // ---- MFMA: 2 k-steps of 32, split-precision (3 products), verbatim ----
        #pragma unroll
        for (int ks = 0; ks < 2; ++ks) {
            short8 a0h = *(const short8*)(Ah + (32 * wm + lr) * 72 + 32 * ks + 8 * lk);
            short8 a1h = *(const short8*)(Ah + (32 * wm + 16 + lr) * 72 + 32 * ks + 8 * lk);
            short8 a0l = *(const short8*)(Al + (32 * wm + lr) * 72 + 32 * ks + 8 * lk);
            short8 a1l = *(const short8*)(Al + (32 * wm + 16 + lr) * 72 + 32 * ks + 8 * lk);
            #pragma unroll
            for (int nj = 0; nj < 4; ++nj) {
                short8 bh = *(const short8*)(Bh + (64 * wn + 16 * nj + lr) * 72 + 32 * ks + 8 * lk);
                short8 bl = *(const short8*)(Bl + (64 * wn + 16 * nj + lr) * 72 + 32 * ks + 8 * lk);
                acc[0][nj] = __builtin_amdgcn_mfma_f32_16x16x32_bf16(a0h, bh, acc[0][nj], 0, 0, 0);
                acc[0][nj] = __builtin_amdgcn_mfma_f32_16x16x32_bf16(a0h, bl, acc[0][nj], 0, 0, 0);
                acc[0][nj] = __builtin_amdgcn_mfma_f32_16x16x32_bf16(a0l, bh, acc[0][nj], 0, 0, 0);
                acc[1][nj] = __builtin_amdgcn_mfma_f32_16x16x32_bf16(a1h, bh, acc[1][nj], 0, 0, 0);
                acc[1][nj] = __builtin_amdgcn_mfma_f32_16x16x32_bf16(a1h, bl, acc[1][nj], 0, 0, 0);
                acc[1][nj] = __builtin_amdgcn_mfma_f32_16x16x32_bf16(a1l, bh, acc[1][nj], 0, 0, 0);
            }
        }
        __syncthreads();
    }

    // ---- store Y ----
    float* Yb = Y + rowbase * OUTDIM;
    #pragma unroll
    for (int mi = 0; mi < 2; ++mi)
        #pragma unroll
        for (int nj = 0; nj < 4; ++nj)
            #pragma unroll
            for (int r = 0; r < 4; ++r) {
                int t = 32 * wm + 16 * mi + 4 * lk + r;
                int o = 64 * wn + 16 * nj + lr;
                Yb[(size_t)t * OUTDIM + o] = acc[mi][nj][r];
            }
}

// ---------------------------------------------------------------------------
extern "C" void kernel_launch(void* const* d_in, const int* in_sizes, int n_in,
                              void* d_out, int out_size, void* d_ws, size_t ws_size,
                              hipStream_t stream) {
    const float* X         = (const float*)d_in[0];
    const float* nu_log    = (const float*)d_in[1];
    const float* theta_log = (const float*)d_in[2];
    const float* B_re      = (const float*)d_in[3];
    const float* B_im      = (const float*)d_in[4];
    const float* C_re      = (const float*)d_in[5];
    const float* C_im      = (const float*)d_in[6];
    const float* D         = (const float*)d_in[7];
    float* Y = (float*)d_out;

    // workspace layout (~97.7 MB)
    float2*         BX     = (float2*)d_ws;                                        // 64 MB
    unsigned int*   hloc   = (unsigned int*)((char*)d_ws + (size_t)67108864);      // 32 MB
    float2*         EC     = (float2*)((char*)d_ws + (size_t)100663296);           // 1 MB
    float2*         lampow = (float2*)((char*)d_ws + (size_t)101711872);           // 128 KB
    unsigned short* Wbx_hi = (unsigned short*)((char*)d_ws + (size_t)101842944);   // 128 KB
    unsigned short* Wbx_lo = (unsigned short*)((char*)d_ws + (size_t)101974016);   // 128 KB
    unsigned short* Wy_hi  = (unsigned short*)((char*)d_ws + (size_t)102105088);   // 160 KB
    unsigned short* Wy_lo  = (unsigned short*)((char*)d_ws + (size_t)102268928);   // 160 KB

    hipLaunchKernelGGL(k_prep, dim3(640), dim3(256), 0, stream,
                       nu_log, theta_log, B_re, B_im, C_re, C_im, D,
                       Wbx_hi, Wbx_lo, Wy_hi, Wy_lo, lampow);
    hipLaunchKernelGGL(k_bx, dim3(NBATCH * NCH * 2), dim3(256), 0, stream,
                       X, Wbx_hi, Wbx_lo, BX);
    hipLaunchKernelGGL(k_scan, dim3(NBATCH * NCH), dim3(256), 0, stream,
                       nu_log, theta_log, BX, hloc, EC);
    hipLaunchKernelGGL(k_carry, dim3(NBATCH), dim3(256), 0, stream,
                       nu_log, theta_log, EC);
    hipLaunchKernelGGL(k_y, dim3(NBATCH * NCH), dim3(256), 0, stream,
                       X, hloc, EC, lampow, Wy_hi, Wy_lo, Y);
}

// Round 9
// 197.140 us; speedup vs baseline: 1.0568x; 1.0568x over previous
//
#include <hip/hip_runtime.h>
#include <hip/hip_bf16.h>

#define TFULL 4096
#define NBATCH 8
#define INDIM 128
#define OUTDIM 128
#define HIDDIM 256
#define LCH 64
#define NCH (TFULL / LCH)   // 64

typedef float f32x4 __attribute__((ext_vector_type(4)));
typedef short short8 __attribute__((ext_vector_type(8)));

static __device__ __forceinline__ unsigned short f2bf(float f) {
    unsigned int x = __float_as_uint(f);
    x += 0x7fffu + ((x >> 16) & 1u);   // round-to-nearest-even
    return (unsigned short)(x >> 16);
}
static __device__ __forceinline__ unsigned int pack2(float a, float b) {
    return ((unsigned int)f2bf(b) << 16) | (unsigned int)f2bf(a);
}
static __device__ __forceinline__ float bflo(unsigned int u) {
    return __uint_as_float(u << 16);
}
static __device__ __forceinline__ float bfhi(unsigned int u) {
    return __uint_as_float(u & 0xffff0000u);
}
// split fp32 into hi/lo bf16 pair (v ~= hi + lo to ~16.5 mantissa bits)
static __device__ __forceinline__ void split2(float v, unsigned short& hi, unsigned short& lo) {
    hi = f2bf(v);
    lo = f2bf(v - __uint_as_float((unsigned int)hi << 16));
}

// ---------------------------------------------------------------------------
// K0 (proven): precompute hi/lo bf16 weights + lam^(t+1) table.
// ---------------------------------------------------------------------------
__global__ __launch_bounds__(256) void k_prep(
    const float* __restrict__ nu_log, const float* __restrict__ theta_log,
    const float* __restrict__ B_re, const float* __restrict__ B_im,
    const float* __restrict__ C_re, const float* __restrict__ C_im,
    const float* __restrict__ D,
    unsigned short* __restrict__ Wbx_hi, unsigned short* __restrict__ Wbx_lo,
    unsigned short* __restrict__ Wy_hi, unsigned short* __restrict__ Wy_lo,
    float2* __restrict__ lampow)
{
    int f = blockIdx.x * 256 + threadIdx.x;   // grid 640 -> f < 163840
    if (f < 65536) {
        int kk = f & 31, n = (f >> 5) & 255, kc = (f >> 13) & 3, half = f >> 15;
        int g = n >> 6;
        int h = 128 * half + 64 * (g >> 1) + (n & 63);
        int i = 32 * kc + kk;
        float mag = expf(-expf(nu_log[h]));
        float gam = sqrtf(fmaxf(0.f, 1.f - mag * mag));
        float v = gam * ((g & 1) ? B_im[h * INDIM + i] : B_re[h * INDIM + i]);
        unsigned short hi, lo; split2(v, hi, lo);
        Wbx_hi[f] = hi; Wbx_lo[f] = lo;
    } else if (f < 147456) {
        int q = f - 65536;
        int kk = q & 63, o = (q >> 6) & 127, kc = q >> 13;
        int k = 64 * kc + kk;
        float v;
        if (k < 512) {
            int h = k >> 1;
            v = (k & 1) ? -C_im[o * HIDDIM + h] : C_re[o * HIDDIM + h];
        } else {
            v = D[o * INDIM + (k - 512)];
        }
        unsigned short hi, lo; split2(v, hi, lo);
        Wy_hi[q] = hi; Wy_lo[q] = lo;
    } else {
        int l = f - 147456;                   // [0, 16384)
        int h = l & 255, tl = l >> 8;
        float nu = expf(nu_log[h]), th = expf(theta_log[h]);
        float kf = (float)(tl + 1);
        float m = expf(-kf * nu);
        lampow[l] = make_float2(m * cosf(kf * th), m * sinf(kf * th));
    }
}

// ---------------------------------------------------------------------------
// K1a (R7-proven verbatim): split-precision MFMA GEMM BX (M=64 t, N=256,
//      K=128) per (b, chunk, h-half). Serial stage phase (no prefetch —
//      R8's prefetch spilled). Writes BX fp32 float2 to ws.
// ---------------------------------------------------------------------------
__global__ __launch_bounds__(256) void k_bx(
    const float* __restrict__ X,
    const unsigned short* __restrict__ Wbx_hi,
    const unsigned short* __restrict__ Wbx_lo,
    float2* __restrict__ BX)
{
    __shared__ unsigned short sm[25600];   // 51200 B
    unsigned short* Ash = sm;              // [64][40]
    unsigned short* Asl = sm + 2560;       // [64][40]
    unsigned short* Bsh = sm + 5120;       // [256][40]
    unsigned short* Bsl = sm + 15360;      // [256][40]

    const int tid = threadIdx.x;
    const int blk = blockIdx.x;
    const int b = blk >> 7, c = (blk >> 1) & 63, half = blk & 1;
    const size_t rowbase = (size_t)(b * TFULL + c * LCH);

    f32x4 acc[2][8];
    #pragma unroll
    for (int mi = 0; mi < 2; ++mi)
        #pragma unroll
        for (int j = 0; j < 8; ++j) acc[mi][j] = (f32x4){0.f, 0.f, 0.f, 0.f};

    const int w = tid >> 6, l = tid & 63;
    const int wm = w >> 1, wn = w & 1;
    const int lr = l & 15, lk = l >> 4;
    const unsigned short* wch_h = Wbx_hi + half * 32768;
    const unsigned short* wch_l = Wbx_lo + half * 32768;

    for (int kc = 0; kc < 4; ++kc) {
        __syncthreads();
        // ---- stage B hi/lo [256][40] from contiguous 16KB weight chunks ----
        {
            const uint4* sh = (const uint4*)(wch_h + kc * 8192);
            const uint4* sl = (const uint4*)(wch_l + kc * 8192);
            #pragma unroll
            for (int j = 0; j < 4; ++j) {
                uint4 vh = sh[tid + j * 256];
                uint4 vl = sl[tid + j * 256];
                int n = (tid >> 2) + 64 * j, kq = 8 * (tid & 3);
                *(uint4*)(Bsh + n * 40 + kq) = vh;
                *(uint4*)(Bsl + n * 40 + kq) = vl;
            }
        }
        // ---- stage A hi/lo [64][40] = split-bf16(X chunk cols 32kc..+32) ----
        {
            int t = tid >> 2, q = tid & 3;
            const float* Xr = X + (rowbase + t) * INDIM + 32 * kc + 8 * q;
            float4 v0 = *(const float4*)(Xr);
            float4 v1 = *(const float4*)(Xr + 4);
            float xs[8] = {v0.x, v0.y, v0.z, v0.w, v1.x, v1.y, v1.z, v1.w};
            unsigned int* Ah32 = (unsigned int*)Ash + t * 20 + 4 * q;
            unsigned int* Al32 = (unsigned int*)Asl + t * 20 + 4 * q;
            #pragma unroll
            for (int e = 0; e < 4; ++e) {
                unsigned short h0, l0, h1, l1;
                split2(xs[2 * e], h0, l0);
                split2(xs[2 * e + 1], h1, l1);
                Ah32[e] = ((unsigned int)h1 << 16) | h0;
                Al32[e] = ((unsigned int)l1 << 16) | l0;
            }
        }
        __syncthreads();
        // ---- MFMA: split-precision (3 products) ----
        short8 a0h = *(const short8*)(Ash + (32 * wm + lr) * 40 + 8 * lk);
        short8 a1h = *(const short8*)(Ash + (32 * wm + 16 + lr) * 40 + 8 * lk);
        short8 a0l = *(const short8*)(Asl + (32 * wm + lr) * 40 + 8 * lk);
        short8 a1l = *(const short8*)(Asl + (32 * wm + 16 + lr) * 40 + 8 * lk);
        #pragma unroll
        for (int j = 0; j < 8; ++j) {
            short8 bh = *(const short8*)(Bsh + (128 * wn + 16 * j + lr) * 40 + 8 * lk);
            short8 bl = *(const short8*)(Bsl + (128 * wn + 16 * j + lr) * 40 + 8 * lk);
            acc[0][j] = __builtin_amdgcn_mfma_f32_16x16x32_bf16(a0h, bh, acc[0][j], 0, 0, 0);
            acc[0][j] = __builtin_amdgcn_mfma_f32_16x16x32_bf16(a0l, bh, acc[0][j], 0, 0, 0);
            acc[0][j] = __builtin_amdgcn_mfma_f32_16x16x32_bf16(a0h, bl, acc[0][j], 0, 0, 0);
            acc[1][j] = __builtin_amdgcn_mfma_f32_16x16x32_bf16(a1h, bh, acc[1][j], 0, 0, 0);
            acc[1][j] = __builtin_amdgcn_mfma_f32_16x16x32_bf16(a1l, bh, acc[1][j], 0, 0, 0);
            acc[1][j] = __builtin_amdgcn_mfma_f32_16x16x32_bf16(a1h, bl, acc[1][j], 0, 0, 0);
        }
    }

    // ---- store BX fp32: h = 128*half + 64*wn + 16*j + lr ----
    #pragma unroll
    for (int mi = 0; mi < 2; ++mi)
        #pragma unroll
        for (int j = 0; j < 4; ++j)
            #pragma unroll
            for (int r = 0; r < 4; ++r) {
                int t = 32 * wm + 16 * mi + 4 * lk + r;
                int h = 128 * half + 64 * wn + 16 * j + lr;
                BX[(rowbase + t) * HIDDIM + h] =
                    make_float2(acc[mi][j][r], acc[mi][j + 4][r]);
            }
}

// ---------------------------------------------------------------------------
// K1b (R7-proven): pipelined sequential scan; bf16x2 h out; chunk-end -> EC.
// ---------------------------------------------------------------------------
__global__ __launch_bounds__(256) void k_scan(
    const float* __restrict__ nu_log, const float* __restrict__ theta_log,
    const float2* __restrict__ BX, unsigned int* __restrict__ hloc,
    float2* __restrict__ EC)
{
    const int b = blockIdx.x >> 6, c = blockIdx.x & 63;
    const int h = threadIdx.x;
    const size_t rowbase = (size_t)(b * TFULL + c * LCH);

    float nu = expf(nu_log[h]), th = expf(theta_log[h]);
    float mag = expf(-nu);
    float lre = mag * cosf(th), lim = mag * sinf(th);
    float sre = 0.f, sim = 0.f;
    const float2* p = BX + rowbase * HIDDIM + h;
    unsigned int* q = hloc + rowbase * HIDDIM + h;
    for (int t0 = 0; t0 < LCH; t0 += 8) {
        float2 v[8];
        #pragma unroll
        for (int j = 0; j < 8; ++j) v[j] = p[(size_t)(t0 + j) * HIDDIM];
        unsigned int o[8];
        #pragma unroll
        for (int j = 0; j < 8; ++j) {
            float nre = fmaf(lre, sre, fmaf(-lim, sim, v[j].x));
            float nim = fmaf(lre, sim, fmaf(lim, sre, v[j].y));
            sre = nre; sim = nim;
            o[j] = pack2(sre, sim);
        }
        #pragma unroll
        for (int j = 0; j < 8; ++j) q[(size_t)(t0 + j) * HIDDIM] = o[j];
    }
    EC[((size_t)b * NCH + c) * HIDDIM + h] = make_float2(sre, sim);
}

// ---------------------------------------------------------------------------
// K2 (R7-proven): pipelined serial carry.
// ---------------------------------------------------------------------------
__global__ __launch_bounds__(256) void k_carry(
    const float* __restrict__ nu_log, const float* __restrict__ theta_log,
    float2* __restrict__ EC)
{
    int b = blockIdx.x, h = threadIdx.x;
    float nu = expf(nu_log[h]), th = expf(theta_log[h]);
    float m = expf(-(float)LCH * nu);
    float Lre = m * cosf((float)LCH * th);
    float Lim = m * sinf((float)LCH * th);
    float cre = 0.f, cim = 0.f;
    float2* base = EC + (size_t)b * NCH * HIDDIM + h;
    for (int c0 = 0; c0 < NCH; c0 += 8) {
        float2 e[8];
        #pragma unroll
        for (int j = 0; j < 8; ++j) e[j] = base[(size_t)(c0 + j) * HIDDIM];
        float2 wv[8];
        #pragma unroll
        for (int j = 0; j < 8; ++j) {
            wv[j] = make_float2(cre, cim);
            float nre = e[j].x + Lre * cre - Lim * cim;
            float nim = e[j].y + Lre * cim + Lim * cre;
            cre = nre; cim = nim;
        }
        #pragma unroll
        for (int j = 0; j < 8; ++j) base[(size_t)(c0 + j) * HIDDIM] = wv[j];
    }
}

// ---------------------------------------------------------------------------
// K3 (R7 structure, serial staging; LDS diet 72->68 pad): split-precision
//     MFMA GEMM Y (M=64 t, N=128 o, K=640). LDS 54272 B -> 3 blocks/CU
//     (was 57344 B -> 2 blocks/CU). Row stride 136 B = 34 banks: B-frag
//     read banks (2*row) mod 32, all 16 rows distinct -> conflict-free.
// ---------------------------------------------------------------------------
__global__ __launch_bounds__(256) void k_y(
    const float* __restrict__ X, const unsigned int* __restrict__ hloc,
    const float2* __restrict__ EC, const float2* __restrict__ lampow,
    const unsigned short* __restrict__ Wy_hi,
    const unsigned short* __restrict__ Wy_lo, float* __restrict__ Y)
{
    __shared__ unsigned short sm[26112];  // 52224 B
    unsigned short* Ah = sm;              // [64][68]
    unsigned short* Al = sm + 4352;       // [64][68]
    unsigned short* Bh = sm + 8704;       // [128][68]
    unsigned short* Bl = sm + 17408;      // [128][68]
    __shared__ float2 carryS[256];

    const int tid = threadIdx.x;
    const int b = blockIdx.x >> 6, c = blockIdx.x & 63;
    const size_t rowbase = (size_t)(b * TFULL + c * LCH);

    carryS[tid] = EC[((size_t)b * NCH + c) * HIDDIM + tid];

    f32x4 acc[2][4];
    #pragma unroll
    for (int mi = 0; mi < 2; ++mi)
        #pragma unroll
        for (int nj = 0; nj < 4; ++nj) acc[mi][nj] = (f32x4){0.f, 0.f, 0.f, 0.f};

    const int w = tid >> 6, l = tid & 63;
    const int wm = w >> 1, wn = w & 1;
    const int lr = l & 15, lk = l >> 4;

    for (int kc = 0; kc < 10; ++kc) {
        __syncthreads();
        // ---- stage B hi/lo [128][68] from contiguous 16KB weight chunks ----
        {
            const uint4* sh = (const uint4*)(Wy_hi + kc * 8192);
            const uint4* sl = (const uint4*)(Wy_lo + kc * 8192);
            #pragma unroll
            for (int j = 0; j < 4; ++j) {
                uint4 vh = sh[tid + j * 256];
                uint4 vl = sl[tid + j * 256];
                int o = (tid >> 3) + 32 * j, kq = 8 * (tid & 7);
                *(uint4*)(Bh + o * 68 + kq) = vh;
                *(uint4*)(Bl + o * 68 + kq) = vl;
            }
        }
        // ---- stage A hi/lo [64][68] ----
        if (kc < 8) {
            #pragma unroll
            for (int s = 0; s < 2; ++s) {
                int f = s * 256 + tid;
                int t = f >> 3, slot = f & 7;
                uint4 u = *(const uint4*)(hloc + (rowbase + t) * HIDDIM + 32 * kc + 4 * slot);
                unsigned int* Arh = (unsigned int*)Ah + t * 34 + 4 * slot;
                unsigned int* Arl = (unsigned int*)Al + t * 34 + 4 * slot;
                const unsigned int* uu = (const unsigned int*)&u;
                #pragma unroll
                for (int e = 0; e < 4; ++e) {
                    int h = 32 * kc + 4 * slot + e;
                    float2 lp = lampow[t * HIDDIM + h];
                    float2 cr = carryS[h];
                    float hre = bflo(uu[e]) + lp.x * cr.x - lp.y * cr.y;
                    float him = bfhi(uu[e]) + lp.x * cr.y + lp.y * cr.x;
                    unsigned short rh, rl, ih, il;
                    split2(hre, rh, rl); split2(him, ih, il);
                    Arh[e] = ((unsigned int)ih << 16) | rh;
                    Arl[e] = ((unsigned int)il << 16) | rl;
                }
            }
        } else {
            int i0 = (kc - 8) * 64;
            #pragma unroll
            for (int s = 0; s < 4; ++s) {
                int f = s * 256 + tid;
                int t = f >> 4, slot = f & 15;
                float4 v = *(const float4*)(X + (rowbase + t) * INDIM + i0 + 4 * slot);
                unsigned short h0,l0,h1,l1,h2,l2,h3,l3;
                split2(v.x,h0,l0); split2(v.y,h1,l1); split2(v.z,h2,l2); split2(v.w,h3,l3);
                unsigned int* Arh = (unsigned int*)Ah + t * 34 + 2 * slot;
                unsigned int* Arl = (unsigned int*)Al + t * 34 + 2 * slot;
                Arh[0] = ((unsigned int)h1 << 16) | h0;
                Arh[1] = ((unsigned int)h3 << 16) | h2;
                Arl[0] = ((unsigned int)l1 << 16) | l0;
                Arl[1] = ((unsigned int)l3 << 16) | l2;
            }
        }
        __syncthreads();
        // ---- MFMA: 2 k-steps of 32, split-precision (3 products) ----
        #pragma unroll
        for (int ks = 0; ks < 2; ++ks) {
            short8 a0h = *(const short8*)(Ah + (32 * wm + lr) * 68 + 32 * ks + 8 * lk);
            short8 a1h = *(const short8*)(Ah + (32 * wm + 16 + lr) * 68 + 32 * ks + 8 * lk);
            short8 a0l = *(const short8*)(Al + (32 * wm + lr) * 68 + 32 * ks + 8 * lk);
            short8 a1l = *(const short8*)(Al + (32 * wm + 16 + lr) * 68 + 32 * ks + 8 * lk);
            #pragma unroll
            for (int nj = 0; nj < 4; ++nj) {
                short8 bh = *(const short8*)(Bh + (64 * wn + 16 * nj + lr) * 68 + 32 * ks + 8 * lk);
                short8 bl = *(const short8*)(Bl + (64 * wn + 16 * nj + lr) * 68 + 32 * ks + 8 * lk);
                acc[0][nj] = __builtin_amdgcn_mfma_f32_16x16x32_bf16(a0h, bh, acc[0][nj], 0, 0, 0);
                acc[0][nj] = __builtin_amdgcn_mfma_f32_16x16x32_bf16(a0h, bl, acc[0][nj], 0, 0, 0);
                acc[0][nj] = __builtin_amdgcn_mfma_f32_16x16x32_bf16(a0l, bh, acc[0][nj], 0, 0, 0);
                acc[1][nj] = __builtin_amdgcn_mfma_f32_16x16x32_bf16(a1h, bh, acc[1][nj], 0, 0, 0);
                acc[1][nj] = __builtin_amdgcn_mfma_f32_16x16x32_bf16(a1h, bl, acc[1][nj], 0, 0, 0);
                acc[1][nj] = __builtin_amdgcn_mfma_f32_16x16x32_bf16(a1l, bh, acc[1][nj], 0, 0, 0);
            }
        }
    }

    // ---- store Y ----
    float* Yb = Y + rowbase * OUTDIM;
    #pragma unroll
    for (int mi = 0; mi < 2; ++mi)
        #pragma unroll
        for (int nj = 0; nj < 4; ++nj)
            #pragma unroll
            for (int r = 0; r < 4; ++r) {
                int t = 32 * wm + 16 * mi + 4 * lk + r;
                int o = 64 * wn + 16 * nj + lr;
                Yb[(size_t)t * OUTDIM + o] = acc[mi][nj][r];
            }
}

// ---------------------------------------------------------------------------
extern "C" void kernel_launch(void* const* d_in, const int* in_sizes, int n_in,
                              void* d_out, int out_size, void* d_ws, size_t ws_size,
                              hipStream_t stream) {
    const float* X         = (const float*)d_in[0];
    const float* nu_log    = (const float*)d_in[1];
    const float* theta_log = (const float*)d_in[2];
    const float* B_re      = (const float*)d_in[3];
    const float* B_im      = (const float*)d_in[4];
    const float* C_re      = (const float*)d_in[5];
    const float* C_im      = (const float*)d_in[6];
    const float* D         = (const float*)d_in[7];
    float* Y = (float*)d_out;

    // workspace layout (~97.7 MB)
    float2*         BX     = (float2*)d_ws;                                        // 64 MB
    unsigned int*   hloc   = (unsigned int*)((char*)d_ws + (size_t)67108864);      // 32 MB
    float2*         EC     = (float2*)((char*)d_ws + (size_t)100663296);           // 1 MB
    float2*         lampow = (float2*)((char*)d_ws + (size_t)101711872);           // 128 KB
    unsigned short* Wbx_hi = (unsigned short*)((char*)d_ws + (size_t)101842944);   // 128 KB
    unsigned short* Wbx_lo = (unsigned short*)((char*)d_ws + (size_t)101974016);   // 128 KB
    unsigned short* Wy_hi  = (unsigned short*)((char*)d_ws + (size_t)102105088);   // 160 KB
    unsigned short* Wy_lo  = (unsigned short*)((char*)d_ws + (size_t)102268928);   // 160 KB

    hipLaunchKernelGGL(k_prep, dim3(640), dim3(256), 0, stream,
                       nu_log, theta_log, B_re, B_im, C_re, C_im, D,
                       Wbx_hi, Wbx_lo, Wy_hi, Wy_lo, lampow);
    hipLaunchKernelGGL(k_bx, dim3(NBATCH * NCH * 2), dim3(256), 0, stream,
                       X, Wbx_hi, Wbx_lo, BX);
    hipLaunchKernelGGL(k_scan, dim3(NBATCH * NCH), dim3(256), 0, stream,
                       nu_log, theta_log, BX, hloc, EC);
    hipLaunchKernelGGL(k_carry, dim3(NBATCH), dim3(256), 0, stream,
                       nu_log, theta_log, EC);
    hipLaunchKernelGGL(k_y, dim3(NBATCH * NCH), dim3(256), 0, stream,
                       X, hloc, EC, lampow, Wy_hi, Wy_lo, Y);
}